// Round 8
// baseline (307.711 us; speedup 1.0000x reference)
//
#include <hip/hip_runtime.h>
#include <math.h>

#define LL 2048
#define CC 128
#define BB 16
#define UU 40
#define NT 256
#define NW 4
#define EPSF 1e-5f

// ---------------- reduction helpers ----------------
__device__ __forceinline__ float waveSum(float v) {
#pragma unroll
    for (int off = 1; off < 64; off <<= 1) v += __shfl_xor(v, off, 64);
    return v;
}
__device__ __forceinline__ float waveMax(float v) {
#pragma unroll
    for (int off = 1; off < 64; off <<= 1) v = fmaxf(v, __shfl_xor(v, off, 64));
    return v;
}
__device__ __forceinline__ float waveMin(float v) {
#pragma unroll
    for (int off = 1; off < 64; off <<= 1) v = fminf(v, __shfl_xor(v, off, 64));
    return v;
}
__device__ __forceinline__ float blockSum(float v, volatile float* scr) {
    v = waveSum(v);
    const int lane = threadIdx.x & 63, wid = threadIdx.x >> 6;
    __syncthreads();
    if (lane == 0) scr[wid] = v;
    __syncthreads();
    return scr[0] + scr[1] + scr[2] + scr[3];
}
__device__ __forceinline__ float blockMax(float v, volatile float* scr) {
    v = waveMax(v);
    const int lane = threadIdx.x & 63, wid = threadIdx.x >> 6;
    __syncthreads();
    if (lane == 0) scr[wid] = v;
    __syncthreads();
    return fmaxf(fmaxf(scr[0], scr[1]), fmaxf(scr[2], scr[3]));
}
__device__ __forceinline__ float blockMin(float v, volatile float* scr) {
    v = waveMin(v);
    const int lane = threadIdx.x & 63, wid = threadIdx.x >> 6;
    __syncthreads();
    if (lane == 0) scr[wid] = v;
    __syncthreads();
    return fminf(fminf(scr[0], scr[1]), fminf(scr[2], scr[3]));
}

// ---------------- idx transpose: idx[L][U] int32 -> idxT[U][L] ushort ----------------
__global__ __launch_bounds__(256) void transpose_idx(const int* __restrict__ idx,
                                                     unsigned short* __restrict__ idxT) {
    __shared__ int s[64 * UU];
    const int l0 = blockIdx.x * 64;
    const int tid = threadIdx.x;
    for (int e = tid; e < 64 * UU; e += 256) s[e] = idx[l0 * UU + e];
    __syncthreads();
    for (int e = tid; e < 64 * UU; e += 256) {
        const int u = e >> 6, ll = e & 63;
        idxT[u * LL + l0 + ll] = (unsigned short)s[ll * UU + u];
    }
}

// ---------------- x transpose: x[B,L,C] -> xT[B,C,L] ----------------
__global__ __launch_bounds__(256) void transpose_in(const float* __restrict__ in,
                                                    float* __restrict__ outp) {
    __shared__ float t[32][33];
    const int b  = blockIdx.z;
    const int c0 = blockIdx.x * 32, l0 = blockIdx.y * 32;
    const int lx = threadIdx.x, ly = threadIdx.y;
    const float* base = in + ((size_t)b * LL + l0) * CC + c0;
#pragma unroll
    for (int i = 0; i < 4; ++i) t[ly + i * 8][lx] = base[(size_t)(ly + i * 8) * CC + lx];
    __syncthreads();
    float* obase = outp + ((size_t)b * CC + c0) * LL + l0;
#pragma unroll
    for (int i = 0; i < 4; ++i) obase[(size_t)(ly + i * 8) * LL + lx] = t[lx][ly + i * 8];
}
// outT [B,C,L] -> out [B,L,C]
__global__ __launch_bounds__(256) void transpose_out(const float* __restrict__ in,
                                                     float* __restrict__ outp) {
    __shared__ float t[32][33];
    const int b  = blockIdx.z;
    const int l0 = blockIdx.x * 32, c0 = blockIdx.y * 32;
    const int lx = threadIdx.x, ly = threadIdx.y;
    const float* base = in + ((size_t)b * CC + c0) * LL + l0;
#pragma unroll
    for (int i = 0; i < 4; ++i) t[ly + i * 8][lx] = base[(size_t)(ly + i * 8) * LL + lx];
    __syncthreads();
    float* obase = outp + ((size_t)b * LL + l0) * CC + c0;
#pragma unroll
    for (int i = 0; i < 4; ++i) obase[(size_t)(ly + i * 8) * CC + lx] = t[lx][ly + i * 8];
}

// ---------------- phase A: stats + M + top-40 per (b,c) ----------------
// lane-local l mapping: l = wid*512 + ln*8 + jj  (jj<8) so idxT loads vectorize
// (ushort4 per u per 4-jj pass). M formula identical to validated agg kernel.
__global__ __launch_bounds__(NT, 4) void phaseA(
    const float* __restrict__ xT,             // [B,C,L]
    const unsigned short* __restrict__ idxT,  // [U,L]
    unsigned short* __restrict__ topg,        // [B*C, U]
    float4* __restrict__ stats,               // [B*C] {vmean,kmx,kmn,0}
    const float* __restrict__ gWq, const float* __restrict__ gbq,
    const float* __restrict__ gWk, const float* __restrict__ gbk,
    const float* __restrict__ gWv, const float* __restrict__ gbv)
{
    const int tid = threadIdx.x;
    const int ln  = tid & 63;
    const int wid = tid >> 6;
    const int bc  = blockIdx.x;

    __shared__ __align__(16) float s_xc[LL];
    __shared__ float s_red[NW];
    __shared__ float s_cv[NW * UU];
    __shared__ int   s_ci[NW * UU];
    __shared__ int   s_top[UU];

    const float Wq = *gWq, bq = *gbq, Wk = *gWk, bk = *gbk;
    const float Wv = *gWv, bv = *gbv;

    const float4* xrow4 = (const float4*)(xT + (size_t)bc * LL);
    float4* s_xc4 = (float4*)s_xc;

    // stage + stats
    float vsum = 0.f, kmn = 3.4e38f, kmx = -3.4e38f;
#pragma unroll
    for (int m = 0; m < 2; ++m) {
        const int f = tid + m * 256;
        float4 xv = xrow4[f];
        s_xc4[f] = xv;
        float k0 = __fadd_rn(__fmul_rn(xv.x, Wk), bk);
        float k1 = __fadd_rn(__fmul_rn(xv.y, Wk), bk);
        float k2 = __fadd_rn(__fmul_rn(xv.z, Wk), bk);
        float k3 = __fadd_rn(__fmul_rn(xv.w, Wk), bk);
        vsum += __fadd_rn(__fmul_rn(xv.x, Wv), bv) + __fadd_rn(__fmul_rn(xv.y, Wv), bv)
              + __fadd_rn(__fmul_rn(xv.z, Wv), bv) + __fadd_rn(__fmul_rn(xv.w, Wv), bv);
        kmx = fmaxf(kmx, fmaxf(fmaxf(k0, k1), fmaxf(k2, k3)));
        kmn = fminf(kmn, fminf(fminf(k0, k1), fminf(k2, k3)));
    }
    const float vmean  = blockSum(vsum, s_red) * (1.f / (float)LL);
    const float kmxAll = blockMax(kmx, s_red);
    const float kmnAll = blockMin(kmn, s_red);
    if (tid == 0) stats[bc] = make_float4(vmean, kmxAll, kmnAll, 0.f);
    // barriers in reducers made s_xc visible

    // M inline: two passes of 4 jj each; ~20 live regs per pass (no spill)
    const int lbase = wid * 512 + ln * 8;
    float mloc[8];
#pragma unroll
    for (int pass = 0; pass < 2; ++pass) {
        const int jj0 = pass * 4;
        float  mx0 = -3.4e38f, mx1 = -3.4e38f, mx2 = -3.4e38f, mx3 = -3.4e38f;
        float  mn0 =  3.4e38f, mn1 =  3.4e38f, mn2 =  3.4e38f, mn3 =  3.4e38f;
        double s0 = 0.0, s1 = 0.0, s2 = 0.0, s3 = 0.0;
        const unsigned short* base = idxT + lbase + jj0;
        for (int u = 0; u < UU; ++u) {
            uint2 w = *(const uint2*)(base + (size_t)u * LL);
            const int i0 = (int)(w.x & 0xFFFFu), i1 = (int)(w.x >> 16);
            const int i2 = (int)(w.y & 0xFFFFu), i3 = (int)(w.y >> 16);
            float x0 = s_xc[i0], x1 = s_xc[i1], x2 = s_xc[i2], x3 = s_xc[i3];
            mx0 = fmaxf(mx0, x0); mn0 = fminf(mn0, x0); s0 += (double)x0;
            mx1 = fmaxf(mx1, x1); mn1 = fminf(mn1, x1); s1 += (double)x1;
            mx2 = fmaxf(mx2, x2); mn2 = fminf(mn2, x2); s2 += (double)x2;
            mx3 = fmaxf(mx3, x3); mn3 = fminf(mn3, x3); s3 += (double)x3;
        }
        float  mxa[4] = {mx0, mx1, mx2, mx3};
        float  mna[4] = {mn0, mn1, mn2, mn3};
        double sma[4] = {s0, s1, s2, s3};
#pragma unroll
        for (int q = 0; q < 4; ++q) {
            const float xo = s_xc[lbase + jj0 + q];
            const float xH = (Wk >= 0.f) ? mxa[q] : mna[q];
            const float xL = (Wk >= 0.f) ? mna[q] : mxa[q];
            const float kH = __fadd_rn(__fmul_rn(xH, Wk), bk);
            const float kL = __fadd_rn(__fmul_rn(xL, Wk), bk);
            const float q_ = __fadd_rn(__fmul_rn(xo, Wq), bq);
            const float t1 = __fmul_rn(q_, (q_ >= 0.f) ? kH : kL);
            const double ks = (double)Wk * sma[q] + 40.0 * (double)bk;
            const float t2 = (float)(((double)q_ * ks) * (1.0 / 2048.0));
            mloc[jj0 + q] = __fsub_rn(t1, t2);
        }
    }

    // per-wave top-40 (shuffles only)
    float wbv = mloc[0]; int wbi = lbase;
#pragma unroll
    for (int j = 1; j < 8; ++j)
        if (mloc[j] > wbv) { wbv = mloc[j]; wbi = lbase + j; }

    for (int t = 0; t < UU; ++t) {
        float rv = wbv; int ri = wbi;
#pragma unroll
        for (int off = 1; off < 64; off <<= 1) {
            float ov = __shfl_xor(rv, off, 64);
            int   oi = __shfl_xor(ri, off, 64);
            if (ov > rv || (ov == rv && oi < ri)) { rv = ov; ri = oi; }
        }
        if (ln == 0) { s_cv[wid * UU + t] = rv; s_ci[wid * UU + t] = ri; }
        if (wbi == ri) {
#pragma unroll
            for (int j = 0; j < 8; ++j) if (lbase + j == ri) mloc[j] = -3.4e38f;
            wbv = mloc[0]; wbi = lbase;
#pragma unroll
            for (int j = 1; j < 8; ++j)
                if (mloc[j] > wbv) { wbv = mloc[j]; wbi = lbase + j; }
        }
    }
    __syncthreads();

    // merge 4x40 -> global top-40 (wave 0)
    if (wid == 0) {
        float c0v = s_cv[ln],      c1v = s_cv[ln + 64];
        int   c0i = s_ci[ln],      c1i = s_ci[ln + 64];
        float c2v = (ln < 32) ? s_cv[ln + 128] : -3.4e38f;
        int   c2i = (ln < 32) ? s_ci[ln + 128] : (LL + 1);
        for (int t = 0; t < UU; ++t) {
            float rv = c0v; int ri = c0i;
            if (c1v > rv || (c1v == rv && c1i < ri)) { rv = c1v; ri = c1i; }
            if (c2v > rv || (c2v == rv && c2i < ri)) { rv = c2v; ri = c2i; }
#pragma unroll
            for (int off = 1; off < 64; off <<= 1) {
                float ov = __shfl_xor(rv, off, 64);
                int   oi = __shfl_xor(ri, off, 64);
                if (ov > rv || (ov == rv && oi < ri)) { rv = ov; ri = oi; }
            }
            if (ln == 0) s_top[t] = ri;
            if (c0i == ri) c0v = -3.4e38f;
            else if (c1i == ri) c1v = -3.4e38f;
            else if (c2i == ri) c2v = -3.4e38f;
        }
    }
    __syncthreads();
    if (tid < UU) topg[(size_t)bc * UU + tid] = (unsigned short)s_top[tid];
}

// ---------------- phase BC: softmax rows + scatter + LN/FFN/LN, 1 wave/row ----------------
__global__ __launch_bounds__(NT, 4) void phaseBC(
    const float* __restrict__ xT,             // [B,C,L]
    const unsigned short* __restrict__ topg,  // [B*C, U]
    const float4* __restrict__ stats,         // [B*C]
    float* __restrict__ outT,                 // [B,C,L]
    const float* __restrict__ gWq, const float* __restrict__ gbq,
    const float* __restrict__ gWk, const float* __restrict__ gbk,
    const float* __restrict__ gWv, const float* __restrict__ gbv,
    const float* __restrict__ gWo, const float* __restrict__ gbo,
    const float* __restrict__ gw1, const float* __restrict__ gb1,
    const float* __restrict__ gw2, const float* __restrict__ gb2,
    const float* __restrict__ gg1, const float* __restrict__ gbe1,
    const float* __restrict__ gg2, const float* __restrict__ gbe2)
{
    const int tid = threadIdx.x;
    const int ln  = tid & 63;
    const int wid = tid >> 6;
    const int r   = blockIdx.x * 4 + wid;    // row = b*CC + c

    __shared__ __align__(16) float s_ctx[4][LL];

    const float Wq = *gWq, bq = *gbq, Wk = *gWk, bk = *gbk;
    const float Wv = *gWv, bv = *gbv, Wo = *gWo, bo = *gbo;
    const float w1 = *gw1, b1 = *gb1, w2 = *gw2, b2 = *gb2;
    const float g1 = *gg1, be1 = *gbe1, g2 = *gg2, be2 = *gbe2;

    const float*  xrow  = xT + (size_t)r * LL;
    const float4* xrow4 = (const float4*)xrow;
    float4* orow4 = (float4*)(outT + (size_t)r * LL);
    float4* lds4  = (float4*)s_ctx[wid];

    float4 xc[8], kk[8];
#pragma unroll
    for (int m = 0; m < 8; ++m) {
        float4 xv = xrow4[ln + m * 64];
        xc[m] = xv;
        float4 k4;
        k4.x = __fadd_rn(__fmul_rn(xv.x, Wk), bk);
        k4.y = __fadd_rn(__fmul_rn(xv.y, Wk), bk);
        k4.z = __fadd_rn(__fmul_rn(xv.z, Wk), bk);
        k4.w = __fadd_rn(__fmul_rn(xv.w, Wk), bk);
        kk[m] = k4;
    }
    float4 st = stats[r];
    const float vmean = st.x, kmx = st.y, kmn = st.z;
#pragma unroll
    for (int m = 0; m < 8; ++m)
        lds4[ln + m * 64] = make_float4(vmean, vmean, vmean, vmean);

    const unsigned short* tp = topg + (size_t)r * UU;
    for (int g = 0; g < UU / 4; ++g) {
        int p[4]; float qp[4], sm[4];
#pragma unroll
        for (int q = 0; q < 4; ++q) {
            p[q] = (int)tp[g * 4 + q];
            const float xq = xrow[p[q]];
            qp[q] = __fadd_rn(__fmul_rn(xq, Wq), bq);
            sm[q] = (qp[q] >= 0.f) ? __fmul_rn(qp[q], kmx) : __fmul_rn(qp[q], kmn);
        }
        float se[4] = {0.f, 0.f, 0.f, 0.f};
        float sx[4] = {0.f, 0.f, 0.f, 0.f};
#pragma unroll
        for (int m = 0; m < 8; ++m) {
            float4 k4 = kk[m], x4 = xc[m];
#pragma unroll
            for (int q = 0; q < 4; ++q) {
                float e;
                e = __expf(fmaf(qp[q], k4.x, -sm[q])); se[q] += e; sx[q] = fmaf(e, x4.x, sx[q]);
                e = __expf(fmaf(qp[q], k4.y, -sm[q])); se[q] += e; sx[q] = fmaf(e, x4.y, sx[q]);
                e = __expf(fmaf(qp[q], k4.z, -sm[q])); se[q] += e; sx[q] = fmaf(e, x4.z, sx[q]);
                e = __expf(fmaf(qp[q], k4.w, -sm[q])); se[q] += e; sx[q] = fmaf(e, x4.w, sx[q]);
            }
        }
#pragma unroll
        for (int q = 0; q < 4; ++q) {
            const float seA = waveSum(se[q]);
            const float sxA = waveSum(sx[q]);
            // sum(e*v) = Wv*sum(e*x) + bv*sum(e)
            const float upd = (Wv * sxA + bv * seA) / seA;
            if (ln == 0) s_ctx[wid][p[q]] = upd;
        }
    }

    // epilogue (wave-local; same-wave LDS ordering is program-order)
    float4 tt[8];
    float lsum = 0.f;
#pragma unroll
    for (int m = 0; m < 8; ++m) {
        float4 cx = lds4[ln + m * 64], xv = xc[m], tv;
        tv.x = xv.x + __fadd_rn(__fmul_rn(cx.x, Wo), bo);
        tv.y = xv.y + __fadd_rn(__fmul_rn(cx.y, Wo), bo);
        tv.z = xv.z + __fadd_rn(__fmul_rn(cx.z, Wo), bo);
        tv.w = xv.w + __fadd_rn(__fmul_rn(cx.w, Wo), bo);
        tt[m] = tv;
        lsum += tv.x + tv.y + tv.z + tv.w;
    }
    const float mean1 = waveSum(lsum) * (1.f / (float)LL);
    float lss = 0.f;
#pragma unroll
    for (int m = 0; m < 8; ++m) {
        float4 tv = tt[m];
        float d0 = tv.x - mean1, d1 = tv.y - mean1, d2 = tv.z - mean1, d3 = tv.w - mean1;
        lss += d0 * d0 + d1 * d1 + d2 * d2 + d3 * d3;
    }
    const float var1 = waveSum(lss) * (1.f / (float)LL);
    const float rs1 = rsqrtf(var1 + EPSF);

    float lsum2 = 0.f;
#pragma unroll
    for (int m = 0; m < 8; ++m) {
        float4 tv = tt[m], zz;
        {
            float x1 = (tv.x - mean1) * rs1 * g1 + be1;
            float a = x1 * w1 + b1;
            float y = 0.5f * a * (1.f + erff(a * 0.70710678118654752f));
            zz.x = x1 + (y * w2 + b2);
        }
        {
            float x1 = (tv.y - mean1) * rs1 * g1 + be1;
            float a = x1 * w1 + b1;
            float y = 0.5f * a * (1.f + erff(a * 0.70710678118654752f));
            zz.y = x1 + (y * w2 + b2);
        }
        {
            float x1 = (tv.z - mean1) * rs1 * g1 + be1;
            float a = x1 * w1 + b1;
            float y = 0.5f * a * (1.f + erff(a * 0.70710678118654752f));
            zz.z = x1 + (y * w2 + b2);
        }
        {
            float x1 = (tv.w - mean1) * rs1 * g1 + be1;
            float a = x1 * w1 + b1;
            float y = 0.5f * a * (1.f + erff(a * 0.70710678118654752f));
            zz.w = x1 + (y * w2 + b2);
        }
        tt[m] = zz;
        lsum2 += zz.x + zz.y + zz.z + zz.w;
    }
    const float mean2 = waveSum(lsum2) * (1.f / (float)LL);
    float lss2 = 0.f;
#pragma unroll
    for (int m = 0; m < 8; ++m) {
        float4 zz = tt[m];
        float d0 = zz.x - mean2, d1 = zz.y - mean2, d2 = zz.z - mean2, d3 = zz.w - mean2;
        lss2 += d0 * d0 + d1 * d1 + d2 * d2 + d3 * d3;
    }
    const float var2 = waveSum(lss2) * (1.f / (float)LL);
    const float rs2 = rsqrtf(var2 + EPSF);

#pragma unroll
    for (int m = 0; m < 8; ++m) {
        float4 zz = tt[m], oo;
        oo.x = (zz.x - mean2) * rs2 * g2 + be2;
        oo.y = (zz.y - mean2) * rs2 * g2 + be2;
        oo.z = (zz.z - mean2) * rs2 * g2 + be2;
        oo.w = (zz.w - mean2) * rs2 * g2 + be2;
        orow4[ln + m * 64] = oo;
    }
}

// ---------------- fallback (strided, self-contained; only if ws too small) ----------------
__global__ __launch_bounds__(NT) void informer_fallback(
    const float* __restrict__ xin,
    const float* __restrict__ gWq, const float* __restrict__ gbq,
    const float* __restrict__ gWk, const float* __restrict__ gbk,
    const float* __restrict__ gWv, const float* __restrict__ gbv,
    const float* __restrict__ gWo, const float* __restrict__ gbo,
    const float* __restrict__ gw1, const float* __restrict__ gb1,
    const float* __restrict__ gw2, const float* __restrict__ gb2,
    const float* __restrict__ gg1, const float* __restrict__ gbe1,
    const float* __restrict__ gg2, const float* __restrict__ gbe2,
    const int* __restrict__ idx,
    float* __restrict__ outp)
{
    const int tid  = threadIdx.x;
    const int lane = tid & 63;
    const int wid  = tid >> 6;
    const int blk  = blockIdx.x;
    const int b    = blk >> 7;
    const int c    = blk & (CC - 1);

    __shared__ float  s_xc[LL];
    __shared__ float  s_kc[LL];
    __shared__ float  s_v[LL];
    __shared__ float  s_red[NW];
    __shared__ double s_cv[NW * UU];
    __shared__ int    s_ci[NW * UU];
    __shared__ int    s_top[UU];
    __shared__ float  s_upd[UU];

    const float Wq = *gWq, bq = *gbq, Wk = *gWk, bk = *gbk;
    const float Wv = *gWv, bv = *gbv, Wo = *gWo, bo = *gbo;
    const float w1 = *gw1, b1 = *gb1, w2 = *gw2, b2 = *gb2;
    const float g1 = *gg1, be1 = *gbe1, g2 = *gg2, be2 = *gbe2;

    const float* xrow = xin + (size_t)b * LL * CC + c;
    float* orow = outp + (size_t)b * LL * CC + c;

    float vsum = 0.f, kmn = 3.4e38f, kmx = -3.4e38f;
    for (int l = tid; l < LL; l += NT) {
        float xv = xrow[(size_t)l * CC];
        s_xc[l] = xv;
        float kvv = __fadd_rn(__fmul_rn(xv, Wk), bk);
        float vvv = __fadd_rn(__fmul_rn(xv, Wv), bv);
        s_kc[l] = kvv;
        s_v[l] = vvv;
        vsum += vvv;
        kmn = fminf(kmn, kvv);
        kmx = fmaxf(kmx, kvv);
    }
    const float vmean  = blockSum(vsum, s_red) * (1.f / (float)LL);
    const float kmxAll = blockMax(kmx, s_red);
    const float kmnAll = blockMin(kmn, s_red);

    double mloc[8];
#pragma unroll
    for (int j = 0; j < 8; ++j) {
        const int l = tid + NT * j;
        const float qv = __fadd_rn(__fmul_rn(s_xc[l], Wq), bq);
        const double qd = (double)qv;
        const int* row = idx + l * UU;
        float kmaxs = -3.4e38f, kmins = 3.4e38f;
        double ssum = 0.0;
#pragma unroll 8
        for (int u = 0; u < UU; ++u) {
            float kvv = s_kc[row[u]];
            kmaxs = fmaxf(kmaxs, kvv);
            kmins = fminf(kmins, kvv);
            ssum += (double)kvv;
        }
        double qmax = (qd >= 0.0) ? qd * (double)kmaxs : qd * (double)kmins;
        mloc[j] = qmax - qd * ssum * (1.0 / (double)LL);
    }

    double wbv = mloc[0]; int wbi = tid;
#pragma unroll
    for (int j = 1; j < 8; ++j)
        if (mloc[j] > wbv) { wbv = mloc[j]; wbi = tid + NT * j; }

    for (int t = 0; t < UU; ++t) {
        double rv = wbv; int ri = wbi;
#pragma unroll
        for (int off = 1; off < 64; off <<= 1) {
            double ov = __shfl_xor(rv, off, 64);
            int    oi = __shfl_xor(ri, off, 64);
            if (ov > rv || (ov == rv && oi < ri)) { rv = ov; ri = oi; }
        }
        if (lane == 0) { s_cv[wid * UU + t] = rv; s_ci[wid * UU + t] = ri; }
        if (wbi == ri) {
#pragma unroll
            for (int j = 0; j < 8; ++j) if ((tid + NT * j) == ri) mloc[j] = -1e300;
            wbv = mloc[0]; wbi = tid;
#pragma unroll
            for (int j = 1; j < 8; ++j)
                if (mloc[j] > wbv) { wbv = mloc[j]; wbi = tid + NT * j; }
        }
    }
    __syncthreads();

    if (wid == 0) {
        double c0v = s_cv[lane], c1v = s_cv[lane + 64];
        int    c0i = s_ci[lane], c1i = s_ci[lane + 64];
        double c2v = (lane < 32) ? s_cv[lane + 128] : -1e300;
        int    c2i = (lane < 32) ? s_ci[lane + 128] : (LL + 1);
        for (int t = 0; t < UU; ++t) {
            double rv = c0v; int ri = c0i;
            if (c1v > rv || (c1v == rv && c1i < ri)) { rv = c1v; ri = c1i; }
            if (c2v > rv || (c2v == rv && c2i < ri)) { rv = c2v; ri = c2i; }
#pragma unroll
            for (int off = 1; off < 64; off <<= 1) {
                double ov = __shfl_xor(rv, off, 64);
                int    oi = __shfl_xor(ri, off, 64);
                if (ov > rv || (ov == rv && oi < ri)) { rv = ov; ri = oi; }
            }
            if (lane == 0) s_top[t] = ri;
            if (c0i == ri) c0v = -1e300;
            else if (c1i == ri) c1v = -1e300;
            else if (c2i == ri) c2v = -1e300;
        }
    }
    __syncthreads();

    for (int r = 0; r < UU / NW; ++r) {
        const int u = r * NW + wid;
        const int p = s_top[u];
        const float qp = __fadd_rn(__fmul_rn(s_xc[p], Wq), bq);
        const float smax = (qp >= 0.f) ? qp * kmxAll : qp * kmnAll;
        float se = 0.f, sev = 0.f;
        for (int l = lane; l < LL; l += 64) {
            float e = __expf(qp * s_kc[l] - smax);
            se += e;
            sev = fmaf(e, s_v[l], sev);
        }
        se = waveSum(se); sev = waveSum(sev);
        if (lane == 0) s_upd[u] = sev / se;
    }
    __syncthreads();

    for (int l = tid; l < LL; l += NT) s_kc[l] = vmean;
    __syncthreads();
    if (tid < UU) s_kc[s_top[tid]] = s_upd[tid];
    __syncthreads();

    float lsum = 0.f;
    for (int l = tid; l < LL; l += NT) {
        float tv = s_xc[l] + __fadd_rn(__fmul_rn(s_kc[l], Wo), bo);
        s_kc[l] = tv;
        lsum += tv;
    }
    const float mean1 = blockSum(lsum, s_red) * (1.f / (float)LL);
    float lss = 0.f;
    for (int l = tid; l < LL; l += NT) { float d = s_kc[l] - mean1; lss += d * d; }
    const float var1 = blockSum(lss, s_red) * (1.f / (float)LL);
    const float rs1 = rsqrtf(var1 + EPSF);

    float lsum2 = 0.f;
    for (int l = tid; l < LL; l += NT) {
        float x1 = (s_kc[l] - mean1) * rs1 * g1 + be1;
        float a  = x1 * w1 + b1;
        float y  = 0.5f * a * (1.f + erff(a * 0.70710678118654752f));
        y = y * w2 + b2;
        float z = x1 + y;
        s_kc[l] = z;
        lsum2 += z;
    }
    const float mean2 = blockSum(lsum2, s_red) * (1.f / (float)LL);
    float lss2 = 0.f;
    for (int l = tid; l < LL; l += NT) { float d = s_kc[l] - mean2; lss2 += d * d; }
    const float var2 = blockSum(lss2, s_red) * (1.f / (float)LL);
    const float rs2 = rsqrtf(var2 + EPSF);

    for (int l = tid; l < LL; l += NT)
        orow[(size_t)l * CC] = (s_kc[l] - mean2) * rs2 * g2 + be2;
}

extern "C" void kernel_launch(void* const* d_in, const int* in_sizes, int n_in,
                              void* d_out, int out_size, void* d_ws, size_t ws_size,
                              hipStream_t stream) {
    const float* x   = (const float*)d_in[0];
    const float* Wq  = (const float*)d_in[1];
    const float* bq  = (const float*)d_in[2];
    const float* Wk  = (const float*)d_in[3];
    const float* bk  = (const float*)d_in[4];
    const float* Wv  = (const float*)d_in[5];
    const float* bv  = (const float*)d_in[6];
    const float* Wo  = (const float*)d_in[7];
    const float* bo  = (const float*)d_in[8];
    const float* w1  = (const float*)d_in[9];
    const float* b1  = (const float*)d_in[10];
    const float* w2  = (const float*)d_in[11];
    const float* b2  = (const float*)d_in[12];
    const float* g1  = (const float*)d_in[13];
    const float* be1 = (const float*)d_in[14];
    const float* g2  = (const float*)d_in[15];
    const float* be2 = (const float*)d_in[16];
    const int*   idx = (const int*)d_in[17];
    float* out = (float*)d_out;

    const size_t SZ = (size_t)BB * LL * CC * sizeof(float);  // 16 MB

    if (ws_size >= 2 * SZ) {
        float* xT   = (float*)d_ws;
        float* outT = (float*)((char*)d_ws + SZ);
        // d_out-head scratch (all overwritten by transpose_out at the end):
        unsigned short* idxT = (unsigned short*)d_out;                    // 160 KB
        unsigned short* topg = (unsigned short*)((char*)d_out + 512 * 1024);  // 160 KB
        float4*         stat = (float4*)((char*)d_out + 1024 * 1024);     // 32 KB

        transpose_idx<<<dim3(LL / 64), dim3(256), 0, stream>>>(idx, idxT);
        transpose_in<<<dim3(CC / 32, LL / 32, BB), dim3(32, 8), 0, stream>>>(x, xT);
        phaseA<<<dim3(BB * CC), dim3(NT), 0, stream>>>(
            xT, idxT, topg, stat, Wq, bq, Wk, bk, Wv, bv);
        phaseBC<<<dim3(BB * CC / 4), dim3(NT), 0, stream>>>(
            xT, topg, stat, outT, Wq, bq, Wk, bk, Wv, bv, Wo, bo,
            w1, b1, w2, b2, g1, be1, g2, be2);
        transpose_out<<<dim3(LL / 32, CC / 32, BB), dim3(32, 8), 0, stream>>>(outT, out);
    } else {
        informer_fallback<<<dim3(BB * CC), dim3(NT), 0, stream>>>(
            x, Wq, bq, Wk, bk, Wv, bv, Wo, bo, w1, b1, w2, b2,
            g1, be1, g2, be2, idx, out);
    }
}

// Round 9
// 235.005 us; speedup vs baseline: 1.3094x; 1.3094x over previous
//
#include <hip/hip_runtime.h>
#include <math.h>

#define LL 2048
#define CC 128
#define BB 16
#define UU 40
#define NT 256
#define NW 4
#define EPSF 1e-5f

// ---------------- reduction helpers ----------------
__device__ __forceinline__ float waveSum(float v) {
#pragma unroll
    for (int off = 1; off < 64; off <<= 1) v += __shfl_xor(v, off, 64);
    return v;
}
__device__ __forceinline__ float waveMax(float v) {
#pragma unroll
    for (int off = 1; off < 64; off <<= 1) v = fmaxf(v, __shfl_xor(v, off, 64));
    return v;
}
__device__ __forceinline__ float waveMin(float v) {
#pragma unroll
    for (int off = 1; off < 64; off <<= 1) v = fminf(v, __shfl_xor(v, off, 64));
    return v;
}
__device__ __forceinline__ float blockSum(float v, volatile float* scr) {
    v = waveSum(v);
    const int lane = threadIdx.x & 63, wid = threadIdx.x >> 6;
    __syncthreads();
    if (lane == 0) scr[wid] = v;
    __syncthreads();
    return scr[0] + scr[1] + scr[2] + scr[3];
}
__device__ __forceinline__ float blockMax(float v, volatile float* scr) {
    v = waveMax(v);
    const int lane = threadIdx.x & 63, wid = threadIdx.x >> 6;
    __syncthreads();
    if (lane == 0) scr[wid] = v;
    __syncthreads();
    return fmaxf(fmaxf(scr[0], scr[1]), fmaxf(scr[2], scr[3]));
}
__device__ __forceinline__ float blockMin(float v, volatile float* scr) {
    v = waveMin(v);
    const int lane = threadIdx.x & 63, wid = threadIdx.x >> 6;
    __syncthreads();
    if (lane == 0) scr[wid] = v;
    __syncthreads();
    return fminf(fminf(scr[0], scr[1]), fminf(scr[2], scr[3]));
}

// ---------------- transpose kernels ----------------
// dual: z<16 -> x[B,L,C]->xT[B,C,L] ; z>=16 -> M[B,L,C]->MT[B,C,L]
__global__ __launch_bounds__(256) void transpose_dual(
    const float* __restrict__ x,  float* __restrict__ xT,
    const float* __restrict__ M,  float* __restrict__ MT) {
    __shared__ float t[32][33];
    const int z  = blockIdx.z;
    const int b  = (z < BB) ? z : (z - BB);
    const float* in  = (z < BB) ? x  : M;
    float* outp      = (z < BB) ? xT : MT;
    const int c0 = blockIdx.x * 32, l0 = blockIdx.y * 32;
    const int lx = threadIdx.x, ly = threadIdx.y;
    const float* base = in + ((size_t)b * LL + l0) * CC + c0;
#pragma unroll
    for (int i = 0; i < 4; ++i) t[ly + i * 8][lx] = base[(size_t)(ly + i * 8) * CC + lx];
    __syncthreads();
    float* obase = outp + ((size_t)b * CC + c0) * LL + l0;
#pragma unroll
    for (int i = 0; i < 4; ++i) obase[(size_t)(ly + i * 8) * LL + lx] = t[lx][ly + i * 8];
}
__global__ __launch_bounds__(256) void transpose_out(const float* __restrict__ in,
                                                     float* __restrict__ outp) {
    __shared__ float t[32][33];
    const int b  = blockIdx.z;
    const int l0 = blockIdx.x * 32, c0 = blockIdx.y * 32;
    const int lx = threadIdx.x, ly = threadIdx.y;
    const float* base = in + ((size_t)b * CC + c0) * LL + l0;
#pragma unroll
    for (int i = 0; i < 4; ++i) t[ly + i * 8][lx] = base[(size_t)(ly + i * 8) * LL + lx];
    __syncthreads();
    float* obase = outp + ((size_t)b * LL + l0) * CC + c0;
#pragma unroll
    for (int i = 0; i < 4; ++i) obase[(size_t)(ly + i * 8) * CC + lx] = t[lx][ly + i * 8];
}

// ---------------- M aggregate kernel (R5-proven, XCD-swizzled) ----------------
__global__ __launch_bounds__(256) void agg_kernel(
    const float* __restrict__ x, const int* __restrict__ idx,
    const float* __restrict__ gWq, const float* __restrict__ gbq,
    const float* __restrict__ gWk, const float* __restrict__ gbk,
    float* __restrict__ M)
{
    __shared__ int s_idx[8 * UU];
    const int tid = threadIdx.x;
    const int g   = blockIdx.x;
    const int b   = ((g & 7) << 1) | ((g >> 3) & 1);
    const int l0  = (g >> 4) * 8;
    if (tid < 256)          s_idx[tid]       = idx[l0 * UU + tid];
    if (tid < 8 * UU - 256) s_idx[256 + tid] = idx[l0 * UU + 256 + tid];
    __syncthreads();

    const int s = tid & 31;       // c-quad: c = 4s..4s+3
    const int r = tid >> 5;       // row slot
    const int l = l0 + r;
    const float Wq = *gWq, bq = *gbq, Wk = *gWk, bk = *gbk;

    const float4* xb = (const float4*)(x + (size_t)b * LL * CC);
    float4 xo4 = xb[(size_t)l * 32 + s];
    float xo[4] = {xo4.x, xo4.y, xo4.z, xo4.w};

    float  mx[4] = {-3.4e38f, -3.4e38f, -3.4e38f, -3.4e38f};
    float  mn[4] = { 3.4e38f,  3.4e38f,  3.4e38f,  3.4e38f};
    double sm[4] = {0.0, 0.0, 0.0, 0.0};
    const int* rowp = &s_idx[r * UU];
#pragma unroll 8
    for (int u = 0; u < UU; ++u) {
        const int i = rowp[u];
        float4 xv = xb[(size_t)i * 32 + s];
        float xa[4] = {xv.x, xv.y, xv.z, xv.w};
#pragma unroll
        for (int t = 0; t < 4; ++t) {
            mx[t] = fmaxf(mx[t], xa[t]);
            mn[t] = fminf(mn[t], xa[t]);
            sm[t] += (double)xa[t];
        }
    }
    float mo[4];
#pragma unroll
    for (int t = 0; t < 4; ++t) {
        const float xH = (Wk >= 0.f) ? mx[t] : mn[t];
        const float xL = (Wk >= 0.f) ? mn[t] : mx[t];
        const float kH = __fadd_rn(__fmul_rn(xH, Wk), bk);   // = max_u k, bit-exact
        const float kL = __fadd_rn(__fmul_rn(xL, Wk), bk);   // = min_u k, bit-exact
        const float q  = __fadd_rn(__fmul_rn(xo[t], Wq), bq);
        const float t1 = __fmul_rn(q, (q >= 0.f) ? kH : kL); // = max_u f32(q*k_u)
        const double ks = (double)Wk * sm[t] + 40.0 * (double)bk;
        const float t2 = (float)(((double)q * ks) * (1.0 / 2048.0));
        mo[t] = __fsub_rn(t1, t2);
    }
    float4 Mo = make_float4(mo[0], mo[1], mo[2], mo[3]);
    ((float4*)(M + ((size_t)b * LL + l) * CC))[s] = Mo;
}

// ---------------- rowBC: topk + softmax + epilogue, ONE WAVE PER ROW ----------------
// MoT [B,C,L]: holds MT on entry; each wave reads its full M row into registers,
// then (much later) overwrites the same row with the final output. No barriers.
__global__ __launch_bounds__(NT) void rowBC(
    const float* __restrict__ xT,    // [B,C,L]
    float* MoT,                      // [B,C,L] in: M, out: result (row-exclusive)
    const float* __restrict__ gWq, const float* __restrict__ gbq,
    const float* __restrict__ gWk, const float* __restrict__ gbk,
    const float* __restrict__ gWv, const float* __restrict__ gbv,
    const float* __restrict__ gWo, const float* __restrict__ gbo,
    const float* __restrict__ gw1, const float* __restrict__ gb1,
    const float* __restrict__ gw2, const float* __restrict__ gb2,
    const float* __restrict__ gg1, const float* __restrict__ gbe1,
    const float* __restrict__ gg2, const float* __restrict__ gbe2)
{
    const int tid = threadIdx.x;
    const int ln  = tid & 63;
    const int wid = tid >> 6;
    const int r   = blockIdx.x * 4 + wid;   // row = b*CC + c

    __shared__ __align__(16) float s_ctx[4][LL];
    __shared__ int s_top[4][UU];

    const float Wq = *gWq, bq = *gbq, Wk = *gWk, bk = *gbk;
    const float Wv = *gWv, bv = *gbv, Wo = *gWo, bo = *gbo;
    const float w1 = *gw1, b1 = *gb1, w2 = *gw2, b2 = *gb2;
    const float g1 = *gg1, be1 = *gbe1, g2 = *gg2, be2 = *gbe2;

    const float*  xrow  = xT + (size_t)r * LL;
    const float4* xrow4 = (const float4*)xrow;
    float* Mrow = MoT + (size_t)r * LL;
    const float4* mrow4 = (const float4*)Mrow;
    float4* orow4 = (float4*)Mrow;
    float4* lds4  = (float4*)s_ctx[wid];

    // ---- 1: load M row into registers (element l = 4*(ln+64m)+q)
    float4 mv[8];
#pragma unroll
    for (int m = 0; m < 8; ++m) mv[m] = mrow4[ln + m * 64];

    // ---- 2: in-wave top-40 (iterative argmax, ties -> lower index)
    float bvv = -3.4e38f; int bii = LL + 1;
#pragma unroll
    for (int m = 0; m < 8; ++m) {
        const int l0 = 4 * (ln + 64 * m);
        if (mv[m].x > bvv) { bvv = mv[m].x; bii = l0; }
        if (mv[m].y > bvv) { bvv = mv[m].y; bii = l0 + 1; }
        if (mv[m].z > bvv) { bvv = mv[m].z; bii = l0 + 2; }
        if (mv[m].w > bvv) { bvv = mv[m].w; bii = l0 + 3; }
    }
    for (int t = 0; t < UU; ++t) {
        float rv = bvv; int ri = bii;
#pragma unroll
        for (int off = 1; off < 64; off <<= 1) {
            float ov = __shfl_xor(rv, off, 64);
            int   oi = __shfl_xor(ri, off, 64);
            if (ov > rv || (ov == rv && oi < ri)) { rv = ov; ri = oi; }
        }
        if (ln == 0) s_top[wid][t] = ri;
        if (bii == ri) {   // owner lane: invalidate + rescan
#pragma unroll
            for (int m = 0; m < 8; ++m) {
                const int l0 = 4 * (ln + 64 * m);
                if (l0     == ri) mv[m].x = -3.4e38f;
                if (l0 + 1 == ri) mv[m].y = -3.4e38f;
                if (l0 + 2 == ri) mv[m].z = -3.4e38f;
                if (l0 + 3 == ri) mv[m].w = -3.4e38f;
            }
            bvv = -3.4e38f; bii = LL + 1;
#pragma unroll
            for (int m = 0; m < 8; ++m) {
                const int l0 = 4 * (ln + 64 * m);
                if (mv[m].x > bvv) { bvv = mv[m].x; bii = l0; }
                if (mv[m].y > bvv) { bvv = mv[m].y; bii = l0 + 1; }
                if (mv[m].z > bvv) { bvv = mv[m].z; bii = l0 + 2; }
                if (mv[m].w > bvv) { bvv = mv[m].w; bii = l0 + 3; }
            }
        }
    }

    // ---- 3: load x row; stats (k aggregates via monotone affine of x)
    float4 xc[8];
    float vsum = 0.f, xmx = -3.4e38f, xmn = 3.4e38f;
#pragma unroll
    for (int m = 0; m < 8; ++m) {
        float4 xv = xrow4[ln + m * 64];
        xc[m] = xv;
        vsum += __fadd_rn(__fmul_rn(xv.x, Wv), bv) + __fadd_rn(__fmul_rn(xv.y, Wv), bv)
              + __fadd_rn(__fmul_rn(xv.z, Wv), bv) + __fadd_rn(__fmul_rn(xv.w, Wv), bv);
        xmx = fmaxf(xmx, fmaxf(fmaxf(xv.x, xv.y), fmaxf(xv.z, xv.w)));
        xmn = fminf(xmn, fminf(fminf(xv.x, xv.y), fminf(xv.z, xv.w)));
    }
    vsum = waveSum(vsum);
    xmx  = waveMax(xmx);
    xmn  = waveMin(xmn);
    const float vmean = vsum * (1.f / (float)LL);
    const float kmx = __fadd_rn(__fmul_rn((Wk >= 0.f) ? xmx : xmn, Wk), bk);
    const float kmn = __fadd_rn(__fmul_rn((Wk >= 0.f) ? xmn : xmx, Wk), bk);

    // ---- 4: ctx = vmean
#pragma unroll
    for (int m = 0; m < 8; ++m)
        lds4[ln + m * 64] = make_float4(vmean, vmean, vmean, vmean);

    // ---- 5: softmax rows, 4 u at a time; scatter upd into wave-private LDS row
    for (int g = 0; g < UU / 4; ++g) {
        int p[4]; float qp[4], sm[4];
#pragma unroll
        for (int q = 0; q < 4; ++q) {
            p[q] = s_top[wid][g * 4 + q];
            const float xq = xrow[p[q]];
            qp[q] = __fadd_rn(__fmul_rn(xq, Wq), bq);
            sm[q] = (qp[q] >= 0.f) ? __fmul_rn(qp[q], kmx) : __fmul_rn(qp[q], kmn);
        }
        float se[4] = {0.f, 0.f, 0.f, 0.f};
        float sx[4] = {0.f, 0.f, 0.f, 0.f};
#pragma unroll
        for (int m = 0; m < 8; ++m) {
            float4 x4 = xc[m];
            float4 k4;
            k4.x = __fadd_rn(__fmul_rn(x4.x, Wk), bk);
            k4.y = __fadd_rn(__fmul_rn(x4.y, Wk), bk);
            k4.z = __fadd_rn(__fmul_rn(x4.z, Wk), bk);
            k4.w = __fadd_rn(__fmul_rn(x4.w, Wk), bk);
#pragma unroll
            for (int q = 0; q < 4; ++q) {
                float e;
                e = __expf(fmaf(qp[q], k4.x, -sm[q])); se[q] += e; sx[q] = fmaf(e, x4.x, sx[q]);
                e = __expf(fmaf(qp[q], k4.y, -sm[q])); se[q] += e; sx[q] = fmaf(e, x4.y, sx[q]);
                e = __expf(fmaf(qp[q], k4.z, -sm[q])); se[q] += e; sx[q] = fmaf(e, x4.z, sx[q]);
                e = __expf(fmaf(qp[q], k4.w, -sm[q])); se[q] += e; sx[q] = fmaf(e, x4.w, sx[q]);
            }
        }
#pragma unroll
        for (int q = 0; q < 4; ++q) {
            const float seA = waveSum(se[q]);
            const float sxA = waveSum(sx[q]);
            const float upd = (Wv * sxA + bv * seA) / seA;   // Σe·v = Wv·Σe·x + bv·Σe
            if (ln == 0) s_ctx[wid][p[q]] = upd;
        }
    }

    // ---- 6: epilogue (wave-local; same-wave LDS ordering is program order)
    float4 tt[8];
    float lsum = 0.f;
#pragma unroll
    for (int m = 0; m < 8; ++m) {
        float4 cx = lds4[ln + m * 64], xv = xc[m], tv;
        tv.x = xv.x + __fadd_rn(__fmul_rn(cx.x, Wo), bo);
        tv.y = xv.y + __fadd_rn(__fmul_rn(cx.y, Wo), bo);
        tv.z = xv.z + __fadd_rn(__fmul_rn(cx.z, Wo), bo);
        tv.w = xv.w + __fadd_rn(__fmul_rn(cx.w, Wo), bo);
        tt[m] = tv;
        lsum += tv.x + tv.y + tv.z + tv.w;
    }
    const float mean1 = waveSum(lsum) * (1.f / (float)LL);
    float lss = 0.f;
#pragma unroll
    for (int m = 0; m < 8; ++m) {
        float4 tv = tt[m];
        float d0 = tv.x - mean1, d1 = tv.y - mean1, d2 = tv.z - mean1, d3 = tv.w - mean1;
        lss += d0 * d0 + d1 * d1 + d2 * d2 + d3 * d3;
    }
    const float var1 = waveSum(lss) * (1.f / (float)LL);
    const float rs1 = rsqrtf(var1 + EPSF);

    float lsum2 = 0.f;
#pragma unroll
    for (int m = 0; m < 8; ++m) {
        float4 tv = tt[m], zz;
        {
            float x1 = (tv.x - mean1) * rs1 * g1 + be1;
            float a = x1 * w1 + b1;
            float y = 0.5f * a * (1.f + erff(a * 0.70710678118654752f));
            zz.x = x1 + (y * w2 + b2);
        }
        {
            float x1 = (tv.y - mean1) * rs1 * g1 + be1;
            float a = x1 * w1 + b1;
            float y = 0.5f * a * (1.f + erff(a * 0.70710678118654752f));
            zz.y = x1 + (y * w2 + b2);
        }
        {
            float x1 = (tv.z - mean1) * rs1 * g1 + be1;
            float a = x1 * w1 + b1;
            float y = 0.5f * a * (1.f + erff(a * 0.70710678118654752f));
            zz.z = x1 + (y * w2 + b2);
        }
        {
            float x1 = (tv.w - mean1) * rs1 * g1 + be1;
            float a = x1 * w1 + b1;
            float y = 0.5f * a * (1.f + erff(a * 0.70710678118654752f));
            zz.w = x1 + (y * w2 + b2);
        }
        tt[m] = zz;
        lsum2 += zz.x + zz.y + zz.z + zz.w;
    }
    const float mean2 = waveSum(lsum2) * (1.f / (float)LL);
    float lss2 = 0.f;
#pragma unroll
    for (int m = 0; m < 8; ++m) {
        float4 zz = tt[m];
        float d0 = zz.x - mean2, d1 = zz.y - mean2, d2 = zz.z - mean2, d3 = zz.w - mean2;
        lss2 += d0 * d0 + d1 * d1 + d2 * d2 + d3 * d3;
    }
    const float var2 = waveSum(lss2) * (1.f / (float)LL);
    const float rs2 = rsqrtf(var2 + EPSF);

#pragma unroll
    for (int m = 0; m < 8; ++m) {
        float4 zz = tt[m], oo;
        oo.x = (zz.x - mean2) * rs2 * g2 + be2;
        oo.y = (zz.y - mean2) * rs2 * g2 + be2;
        oo.z = (zz.z - mean2) * rs2 * g2 + be2;
        oo.w = (zz.w - mean2) * rs2 * g2 + be2;
        orow4[ln + m * 64] = oo;
    }
}

// ---------------- fallback (strided, self-contained; only if ws too small) ----------------
__global__ __launch_bounds__(NT) void informer_fallback(
    const float* __restrict__ xin,
    const float* __restrict__ gWq, const float* __restrict__ gbq,
    const float* __restrict__ gWk, const float* __restrict__ gbk,
    const float* __restrict__ gWv, const float* __restrict__ gbv,
    const float* __restrict__ gWo, const float* __restrict__ gbo,
    const float* __restrict__ gw1, const float* __restrict__ gb1,
    const float* __restrict__ gw2, const float* __restrict__ gb2,
    const float* __restrict__ gg1, const float* __restrict__ gbe1,
    const float* __restrict__ gg2, const float* __restrict__ gbe2,
    const int* __restrict__ idx,
    float* __restrict__ outp)
{
    const int tid  = threadIdx.x;
    const int lane = tid & 63;
    const int wid  = tid >> 6;
    const int blk  = blockIdx.x;
    const int b    = blk >> 7;
    const int c    = blk & (CC - 1);

    __shared__ float  s_xc[LL];
    __shared__ float  s_kc[LL];
    __shared__ float  s_v[LL];
    __shared__ float  s_red[NW];
    __shared__ double s_cv[NW * UU];
    __shared__ int    s_ci[NW * UU];
    __shared__ int    s_top[UU];
    __shared__ float  s_upd[UU];

    const float Wq = *gWq, bq = *gbq, Wk = *gWk, bk = *gbk;
    const float Wv = *gWv, bv = *gbv, Wo = *gWo, bo = *gbo;
    const float w1 = *gw1, b1 = *gb1, w2 = *gw2, b2 = *gb2;
    const float g1 = *gg1, be1 = *gbe1, g2 = *gg2, be2 = *gbe2;

    const float* xrow = xin + (size_t)b * LL * CC + c;
    float* orow = outp + (size_t)b * LL * CC + c;

    float vsum = 0.f, kmn = 3.4e38f, kmx = -3.4e38f;
    for (int l = tid; l < LL; l += NT) {
        float xv = xrow[(size_t)l * CC];
        s_xc[l] = xv;
        float kvv = __fadd_rn(__fmul_rn(xv, Wk), bk);
        float vvv = __fadd_rn(__fmul_rn(xv, Wv), bv);
        s_kc[l] = kvv;
        s_v[l] = vvv;
        vsum += vvv;
        kmn = fminf(kmn, kvv);
        kmx = fmaxf(kmx, kvv);
    }
    const float vmean  = blockSum(vsum, s_red) * (1.f / (float)LL);
    const float kmxAll = blockMax(kmx, s_red);
    const float kmnAll = blockMin(kmn, s_red);

    double mloc[8];
#pragma unroll
    for (int j = 0; j < 8; ++j) {
        const int l = tid + NT * j;
        const float qv = __fadd_rn(__fmul_rn(s_xc[l], Wq), bq);
        const double qd = (double)qv;
        const int* row = idx + l * UU;
        float kmaxs = -3.4e38f, kmins = 3.4e38f;
        double ssum = 0.0;
#pragma unroll 8
        for (int u = 0; u < UU; ++u) {
            float kvv = s_kc[row[u]];
            kmaxs = fmaxf(kmaxs, kvv);
            kmins = fminf(kmins, kvv);
            ssum += (double)kvv;
        }
        double qmax = (qd >= 0.0) ? qd * (double)kmaxs : qd * (double)kmins;
        mloc[j] = qmax - qd * ssum * (1.0 / (double)LL);
    }

    double wbv = mloc[0]; int wbi = tid;
#pragma unroll
    for (int j = 1; j < 8; ++j)
        if (mloc[j] > wbv) { wbv = mloc[j]; wbi = tid + NT * j; }

    for (int t = 0; t < UU; ++t) {
        double rv = wbv; int ri = wbi;
#pragma unroll
        for (int off = 1; off < 64; off <<= 1) {
            double ov = __shfl_xor(rv, off, 64);
            int    oi = __shfl_xor(ri, off, 64);
            if (ov > rv || (ov == rv && oi < ri)) { rv = ov; ri = oi; }
        }
        if (lane == 0) { s_cv[wid * UU + t] = rv; s_ci[wid * UU + t] = ri; }
        if (wbi == ri) {
#pragma unroll
            for (int j = 0; j < 8; ++j) if ((tid + NT * j) == ri) mloc[j] = -1e300;
            wbv = mloc[0]; wbi = tid;
#pragma unroll
            for (int j = 1; j < 8; ++j)
                if (mloc[j] > wbv) { wbv = mloc[j]; wbi = tid + NT * j; }
        }
    }
    __syncthreads();

    if (wid == 0) {
        double c0v = s_cv[lane], c1v = s_cv[lane + 64];
        int    c0i = s_ci[lane], c1i = s_ci[lane + 64];
        double c2v = (lane < 32) ? s_cv[lane + 128] : -1e300;
        int    c2i = (lane < 32) ? s_ci[lane + 128] : (LL + 1);
        for (int t = 0; t < UU; ++t) {
            double rv = c0v; int ri = c0i;
            if (c1v > rv || (c1v == rv && c1i < ri)) { rv = c1v; ri = c1i; }
            if (c2v > rv || (c2v == rv && c2i < ri)) { rv = c2v; ri = c2i; }
#pragma unroll
            for (int off = 1; off < 64; off <<= 1) {
                double ov = __shfl_xor(rv, off, 64);
                int    oi = __shfl_xor(ri, off, 64);
                if (ov > rv || (ov == rv && oi < ri)) { rv = ov; ri = oi; }
            }
            if (lane == 0) s_top[t] = ri;
            if (c0i == ri) c0v = -1e300;
            else if (c1i == ri) c1v = -1e300;
            else if (c2i == ri) c2v = -1e300;
        }
    }
    __syncthreads();

    for (int r = 0; r < UU / NW; ++r) {
        const int u = r * NW + wid;
        const int p = s_top[u];
        const float qp = __fadd_rn(__fmul_rn(s_xc[p], Wq), bq);
        const float smax = (qp >= 0.f) ? qp * kmxAll : qp * kmnAll;
        float se = 0.f, sev = 0.f;
        for (int l = lane; l < LL; l += 64) {
            float e = __expf(qp * s_kc[l] - smax);
            se += e;
            sev = fmaf(e, s_v[l], sev);
        }
        se = waveSum(se); sev = waveSum(sev);
        if (lane == 0) s_upd[u] = sev / se;
    }
    __syncthreads();

    for (int l = tid; l < LL; l += NT) s_kc[l] = vmean;
    __syncthreads();
    if (tid < UU) s_kc[s_top[tid]] = s_upd[tid];
    __syncthreads();

    float lsum = 0.f;
    for (int l = tid; l < LL; l += NT) {
        float tv = s_xc[l] + __fadd_rn(__fmul_rn(s_kc[l], Wo), bo);
        s_kc[l] = tv;
        lsum += tv;
    }
    const float mean1 = blockSum(lsum, s_red) * (1.f / (float)LL);
    float lss = 0.f;
    for (int l = tid; l < LL; l += NT) { float d = s_kc[l] - mean1; lss += d * d; }
    const float var1 = blockSum(lss, s_red) * (1.f / (float)LL);
    const float rs1 = rsqrtf(var1 + EPSF);

    float lsum2 = 0.f;
    for (int l = tid; l < LL; l += NT) {
        float x1 = (s_kc[l] - mean1) * rs1 * g1 + be1;
        float a  = x1 * w1 + b1;
        float y  = 0.5f * a * (1.f + erff(a * 0.70710678118654752f));
        y = y * w2 + b2;
        float z = x1 + y;
        s_kc[l] = z;
        lsum2 += z;
    }
    const float mean2 = blockSum(lsum2, s_red) * (1.f / (float)LL);
    float lss2 = 0.f;
    for (int l = tid; l < LL; l += NT) { float d = s_kc[l] - mean2; lss2 += d * d; }
    const float var2 = blockSum(lss2, s_red) * (1.f / (float)LL);
    const float rs2 = rsqrtf(var2 + EPSF);

    for (int l = tid; l < LL; l += NT)
        orow[(size_t)l * CC] = (s_kc[l] - mean2) * rs2 * g2 + be2;
}

extern "C" void kernel_launch(void* const* d_in, const int* in_sizes, int n_in,
                              void* d_out, int out_size, void* d_ws, size_t ws_size,
                              hipStream_t stream) {
    const float* x   = (const float*)d_in[0];
    const float* Wq  = (const float*)d_in[1];
    const float* bq  = (const float*)d_in[2];
    const float* Wk  = (const float*)d_in[3];
    const float* bk  = (const float*)d_in[4];
    const float* Wv  = (const float*)d_in[5];
    const float* bv  = (const float*)d_in[6];
    const float* Wo  = (const float*)d_in[7];
    const float* bo  = (const float*)d_in[8];
    const float* w1  = (const float*)d_in[9];
    const float* b1  = (const float*)d_in[10];
    const float* w2  = (const float*)d_in[11];
    const float* b2  = (const float*)d_in[12];
    const float* g1  = (const float*)d_in[13];
    const float* be1 = (const float*)d_in[14];
    const float* g2  = (const float*)d_in[15];
    const float* be2 = (const float*)d_in[16];
    const int*   idx = (const int*)d_in[17];
    float* out = (float*)d_out;

    const size_t SZ = (size_t)BB * LL * CC * sizeof(float);  // 16 MB

    if (ws_size >= 2 * SZ) {
        float* xT = (float*)d_ws;
        float* MT = (float*)((char*)d_ws + SZ);   // becomes outT in-place
        // 1) M[B,L,C] into d_out (coalesced writes; overwritten at the end)
        agg_kernel<<<dim3((LL / 8) * BB), dim3(256), 0, stream>>>(x, idx, Wq, bq, Wk, bk, out);
        // 2) transpose x->xT and M->MT in one launch
        transpose_dual<<<dim3(CC / 32, LL / 32, 2 * BB), dim3(32, 8), 0, stream>>>(x, xT, out, MT);
        // 3) per-row wave kernel: topk + softmax + epilogue; writes over MT rows
        rowBC<<<dim3(BB * CC / 4), dim3(NT), 0, stream>>>(
            xT, MT, Wq, bq, Wk, bk, Wv, bv, Wo, bo, w1, b1, w2, b2,
            g1, be1, g2, be2);
        // 4) transpose back into d_out
        transpose_out<<<dim3(LL / 32, CC / 32, BB), dim3(32, 8), 0, stream>>>(MT, out);
    } else {
        informer_fallback<<<dim3(BB * CC), dim3(NT), 0, stream>>>(
            x, Wq, bq, Wk, bk, Wv, bv, Wo, bo, w1, b1, w2, b2,
            g1, be1, g2, be2, idx, out);
    }
}